// Round 15
// baseline (244.909 us; speedup 1.0000x reference)
//
#include <hip/hip_runtime.h>
#include <math.h>

#define NN 4096      // nodes = B*S
#define D 256        // DIN == DOUT
#define RR 8
#define LL 4
#define EE 65536
#define BB 8
#define SS 512
#define HH 8
#define RK 256       // RGAT GEMM K
#define RN 2048      // RGAT GEMM N (R*D)

typedef short bf16x8 __attribute__((ext_vector_type(8)));
typedef float f32x4 __attribute__((ext_vector_type(4)));

__device__ __forceinline__ unsigned short f2bf(float f) {
  unsigned u = __float_as_uint(f);
  unsigned r = (u + 0x7fffu + ((u >> 16) & 1u)) >> 16;
  return (unsigned short)r;
}
__device__ __forceinline__ float bf2f(unsigned short s) {
  return __uint_as_float(((unsigned)s) << 16);
}

__device__ __forceinline__ void gload16(unsigned short* dst, const unsigned short* src) {
  __builtin_amdgcn_global_load_lds(
      (const __attribute__((address_space(1))) void*)src,
      (__attribute__((address_space(3))) void*)dst, 16, 0, 0);
}

// ---------------- split-bf16 MFMA GEMM body (4 waves, 2x2 wave grid) --------
// C[M,N] = (Ah+Al)[M,K] * (Bh+Bl)[N,K]^T (+bias), fp32 accum, 3-term split.
// Double-buffered LDS, 1 barrier/K-step; k-slot XOR swizzle both sides.
template<int BM, int BN, bool F32OUT, bool SPLITOUT>
__device__ __forceinline__ void gemm_body(unsigned short* lds, int bx, int by,
    const unsigned short* __restrict__ Ah, const unsigned short* __restrict__ Al,
    const unsigned short* __restrict__ Bh, const unsigned short* __restrict__ Bl,
    const float* __restrict__ bias,
    float* __restrict__ C, unsigned short* __restrict__ Ch, unsigned short* __restrict__ Cl,
    int M, int N, int K)
{
  constexpr int MF = BM / 32;
  constexpr int NF = BN / 32;
  constexpr int ABUF = BM * 32;
  constexpr int BBUF = BN * 32;
  constexpr int BUFSZ = 2 * ABUF + 2 * BBUF;

  const int t = threadIdx.x;
  const int lane = t & 63;
  const int w = t >> 6;
  const int wm = w >> 1, wn = w & 1;
  const int rb = by * BM;
  const int cb = bx * BN;

  f32x4 acc[MF][NF];
#pragma unroll
  for (int m = 0; m < MF; ++m)
#pragma unroll
    for (int n = 0; n < NF; ++n)
      acc[m][n] = (f32x4){0.f, 0.f, 0.f, 0.f};

  const int srow = t >> 2;
  const int lslot = (t & 3) ^ ((srow >> 1) & 3);
  const unsigned short* gAh = Ah + (size_t)(rb + srow) * K + lslot * 8;
  const unsigned short* gAl = Al + (size_t)(rb + srow) * K + lslot * 8;
  const unsigned short* gBh = Bh + (size_t)(cb + srow) * K + lslot * 8;
  const unsigned short* gBl = Bl + (size_t)(cb + srow) * K + lslot * 8;

  auto stage = [&](int buf, int k0) {
    unsigned short* p = lds + buf * BUFSZ;
#pragma unroll
    for (int i = 0; i < BM / 64; ++i) {
      gload16(p + i * 2048 + t * 8,        gAh + (size_t)i * 64 * K + k0);
      gload16(p + ABUF + i * 2048 + t * 8, gAl + (size_t)i * 64 * K + k0);
    }
#pragma unroll
    for (int i = 0; i < BN / 64; ++i) {
      gload16(p + 2 * ABUF + i * 2048 + t * 8,        gBh + (size_t)i * 64 * K + k0);
      gload16(p + 2 * ABUF + BBUF + i * 2048 + t * 8, gBl + (size_t)i * 64 * K + k0);
    }
  };

  stage(0, 0);
  int cur = 0;
  for (int k0 = 0; k0 < K; k0 += 32) {
    __syncthreads();
    if (k0 + 32 < K) stage(cur ^ 1, k0 + 32);
    const unsigned short* p = lds + cur * BUFSZ;

    bf16x8 ah[MF], al[MF];
#pragma unroll
    for (int m = 0; m < MF; ++m) {
      int row = wm * (BM / 2) + m * 16 + (lane & 15);
      int off = row * 32 + (((lane >> 4) ^ ((row >> 1) & 3)) << 3);
      ah[m] = *(const bf16x8*)(p + off);
      al[m] = *(const bf16x8*)(p + ABUF + off);
    }
#pragma unroll
    for (int n = 0; n < NF; ++n) {
      int brow = wn * (BN / 2) + n * 16 + (lane & 15);
      int boff = brow * 32 + (((lane >> 4) ^ ((brow >> 1) & 3)) << 3);
      bf16x8 bh = *(const bf16x8*)(p + 2 * ABUF + boff);
      bf16x8 bl = *(const bf16x8*)(p + 2 * ABUF + BBUF + boff);
#pragma unroll
      for (int m = 0; m < MF; ++m) {
        acc[m][n] = __builtin_amdgcn_mfma_f32_16x16x32_bf16(ah[m], bh, acc[m][n], 0, 0, 0);
        acc[m][n] = __builtin_amdgcn_mfma_f32_16x16x32_bf16(al[m], bh, acc[m][n], 0, 0, 0);
        acc[m][n] = __builtin_amdgcn_mfma_f32_16x16x32_bf16(ah[m], bl, acc[m][n], 0, 0, 0);
      }
    }
    cur ^= 1;
  }

#pragma unroll
  for (int m = 0; m < MF; ++m) {
#pragma unroll
    for (int n = 0; n < NF; ++n) {
      int row0 = rb + wm * (BM / 2) + m * 16 + (lane >> 4) * 4;
      int col = cb + wn * (BN / 2) + n * 16 + (lane & 15);
      float bv = bias ? bias[col] : 0.f;
#pragma unroll
      for (int j = 0; j < 4; ++j) {
        float v = acc[m][n][j] + bv;
        size_t idx = (size_t)(row0 + j) * N + col;
        if (F32OUT) C[idx] = v;
        if (SPLITOUT) {
          unsigned short hb = f2bf(v);
          Ch[idx] = hb;
          Cl[idx] = f2bf(v - bf2f(hb));
        }
      }
    }
  }
}

// standalone GEMM kernel (qk projection)
template<int BM, int BN, bool F32OUT, bool SPLITOUT>
__global__ __launch_bounds__(256) void gemm_split(
    const unsigned short* __restrict__ Ah, const unsigned short* __restrict__ Al,
    const unsigned short* __restrict__ Bh, const unsigned short* __restrict__ Bl,
    const float* __restrict__ bias,
    float* __restrict__ C, unsigned short* __restrict__ Ch, unsigned short* __restrict__ Cl,
    int M, int N, int K)
{
  __shared__ unsigned short lds[2 * (2 * BM * 32 + 2 * BN * 32)];
  gemm_body<BM, BN, F32OUT, SPLITOUT>(lds, blockIdx.x, blockIdx.y,
      Ah, Al, Bh, Bl, bias, C, Ch, Cl, M, N, K);
}

// ---- merged: CSR fill (blocks 0..255) + first GEMM h=x@Wl^T+bl (blocks 256..511)
__global__ __launch_bounds__(256) void fill_gemm1_k(
    const int* __restrict__ ed, int* __restrict__ cur, int* __restrict__ csr,
    const unsigned short* __restrict__ xh, const unsigned short* __restrict__ xl,
    const unsigned short* __restrict__ wlh, const unsigned short* __restrict__ wll,
    const float* __restrict__ bl,
    unsigned short* __restrict__ hh, unsigned short* __restrict__ hl)
{
  __shared__ unsigned short lds[2 * (2 * 64 * 32 + 2 * 64 * 32)];
  int b = blockIdx.x;
  if (b < 256) {
    int e = b * 256 + threadIdx.x;
    int p = atomicAdd(&cur[ed[e]], 1);
    csr[p] = e;
  } else {
    int b2 = b - 256;
    gemm_body<64, 64, false, true>(lds, b2 & 3, b2 >> 2,
        xh, xl, wlh, wll, bl, nullptr, hh, hl, NN, D, D);
  }
}

// ------- merged: RGAT GEMM (blocks 0..1023, 256 thr 4-wave 128x64 tile,
// ------- 48 KB LDS -> 3 blocks/CU, XCD-chunked col-major swizzle) +
// ------- layer-0 scores (blocks 1024..5119).
__global__ __launch_bounds__(256) void rgat_scores_k(
    const unsigned short* __restrict__ Ah, const unsigned short* __restrict__ Al,
    const unsigned short* __restrict__ Bh, const unsigned short* __restrict__ Bl,
    float* __restrict__ C,
    const float* __restrict__ wa_l, const float* __restrict__ adst_l,
    float* __restrict__ ssrc, float* __restrict__ sdst)
{
  __shared__ unsigned short lds[2 * (2 * 128 * 32 + 2 * 64 * 32)];  // 48 KB
  const int b = blockIdx.x;
  const int t = threadIdx.x;
  if (b < 1024) {
    // T1: chunked XCD swizzle (bijective, 1024 % 8 == 0). Col-major walk:
    // each XCD owns 4 col-panels (B slice 0.25 MB L2-resident) x 32 row-blocks.
    int tb = (b & 7) * 128 + (b >> 3);
    gemm_body<128, 64, true, false>(lds, tb >> 5, tb & 31,
        Ah, Al, Bh, Bl, nullptr, C, nullptr, nullptr, NN, RN, RK);
  } else {
    // layer-0 scores: node n = b - 1024 (A operand == split h)
    float* sh = (float*)lds;
    int n = b - 1024;
    size_t idx = (size_t)n * D + t;
    sh[t] = bf2f(Ah[idx]) + bf2f(Al[idx]);
    __syncthreads();
    int lane = t & 63, wv = t >> 6;
#pragma unroll
    for (int rr = 0; rr < 2; ++rr) {
      int r = wv * 2 + rr;
      const float* wr = wa_l + (size_t)r * D;
      const float* ar = adst_l + (size_t)r * D;
      float s1 = sh[lane] * wr[lane] + sh[lane+64] * wr[lane+64]
               + sh[lane+128] * wr[lane+128] + sh[lane+192] * wr[lane+192];
      float s2 = sh[lane] * ar[lane] + sh[lane+64] * ar[lane+64]
               + sh[lane+128] * ar[lane+128] + sh[lane+192] * ar[lane+192];
#pragma unroll
      for (int o = 32; o; o >>= 1) { s1 += __shfl_down(s1, o); s2 += __shfl_down(s2, o); }
      if (lane == 0) { ssrc[(size_t)r * NN + n] = s1; sdst[(size_t)r * NN + n] = s2; }
    }
  }
}

// ---------------- CSR scan (wave-scan, 2 barriers) ----------------
__global__ __launch_bounds__(1024) void scan_k(const int* __restrict__ cnt,
    int* __restrict__ off, int* __restrict__ cur) {
  __shared__ int wsum[16];
  int t = threadIdx.x;
  int lane = t & 63, wv = t >> 6;
  int base = t * 4;
  int c0 = cnt[base], c1 = cnt[base+1], c2 = cnt[base+2], c3 = cnt[base+3];
  int s = c0 + c1 + c2 + c3;
  // inclusive wave scan of s
  int run = s;
#pragma unroll
  for (int o = 1; o < 64; o <<= 1) {
    int v = __shfl_up(run, o);
    if (lane >= o) run += v;
  }
  if (lane == 63) wsum[wv] = run;
  __syncthreads();
  if (t == 0) {
    int r = 0;
#pragma unroll
    for (int i = 0; i < 16; ++i) { int x = wsum[i]; wsum[i] = r; r += x; }
  }
  __syncthreads();
  int excl = wsum[wv] + run - s;
  off[base] = excl; off[base+1] = excl + c0; off[base+2] = excl + c0 + c1;
  off[base+3] = excl + c0 + c1 + c2;
  cur[base] = excl; cur[base+1] = excl + c0; cur[base+2] = excl + c0 + c1;
  cur[base+3] = excl + c0 + c1 + c2;
  if (t == 1023) off[NN] = EE;
}

// ------- mega prep: cvt(x,Wl) + fold + foldb + transp+wa + edge count --------
// blocks [0,1024): x split; [1024,1088): Wl split; [1088,1600): fold Wq/Wk*W1;
// [1600,1728): fold bias; [1728,3776): Wgat transpose-split + wa dots;
// [3776,4032): edge count. (cnt and wa zeroed by the preceding memset.)
__global__ __launch_bounds__(256) void prep_k(
    const float* __restrict__ x, unsigned short* __restrict__ xh, unsigned short* __restrict__ xl,
    const float* __restrict__ Wl, unsigned short* __restrict__ wlh, unsigned short* __restrict__ wll,
    const float* __restrict__ Wq, const float* __restrict__ Wk, const float* __restrict__ W1,
    unsigned short* __restrict__ fqkh, unsigned short* __restrict__ fqkl,
    const float* __restrict__ b1, const float* __restrict__ bq, const float* __restrict__ bk,
    float* __restrict__ bqk,
    const float* __restrict__ Wgat, const float* __restrict__ asrc,
    unsigned short* __restrict__ th, unsigned short* __restrict__ tl,
    float* __restrict__ wa,
    const int* __restrict__ ed, int* __restrict__ cnt)
{
  __shared__ float s[32][33];
  int b = blockIdx.x, t = threadIdx.x;
  if (b < 1088) {
    const float* src; unsigned short* hi; unsigned short* lo; int i;
    if (b < 1024) { src = x;  hi = xh;  lo = xl;  i = b * 256 + t; }
    else          { src = Wl; hi = wlh; lo = wll; i = (b - 1024) * 256 + t; }
    float4 v = ((const float4*)src)[i];
    ushort4 h, l;
    h.x = f2bf(v.x); l.x = f2bf(v.x - bf2f(h.x));
    h.y = f2bf(v.y); l.y = f2bf(v.y - bf2f(h.y));
    h.z = f2bf(v.z); l.z = f2bf(v.z - bf2f(h.z));
    h.w = f2bf(v.w); l.w = f2bf(v.w - bf2f(h.w));
    ((ushort4*)hi)[i] = h;
    ((ushort4*)lo)[i] = l;
  } else if (b < 1600) {
    int b2 = b - 1088;
    int j = (b2 & 3) * 64 + (t & 63);
    int i = (b2 >> 2) * 4 + (t >> 6);
    const float* row = i < 256 ? Wq + (size_t)i * D : Wk + (size_t)(i - 256) * D;
    float sm = 0.f;
    for (int k = 0; k < D; ++k) sm += row[k] * W1[(size_t)k * D + j];
    size_t idx = (size_t)i * D + j;
    unsigned short hb = f2bf(sm);
    fqkh[idx] = hb;
    fqkl[idx] = f2bf(sm - bf2f(hb));
  } else if (b < 1728) {
    int b2 = b - 1600;
    int idx = b2 * 4 + (t >> 6);
    int lane = t & 63;
    const float* row = idx < 256 ? Wq + (size_t)idx * D : Wk + (size_t)(idx - 256) * D;
    float sm = 0.f;
    for (int i = lane; i < D; i += 64) sm += row[i] * b1[i];
#pragma unroll
    for (int o = 32; o; o >>= 1) sm += __shfl_down(sm, o);
    if (lane == 0) bqk[idx] = sm + (idx < 256 ? bq[idx] : bk[idx - 256]);
  } else if (b < 3776) {
    int b2 = b - 1728;                 // 0..2047: g = l*8+r in [0,32)
    int g = b2 >> 6, bi = (b2 >> 3) & 7, bj = b2 & 7;
    int r = t >> 3, c = (t & 7) * 4;
    float4 v = *(const float4*)(Wgat + ((size_t)g * D + bi * 32 + r) * D + bj * 32 + c);
    s[r][c + 0] = v.x; s[r][c + 1] = v.y; s[r][c + 2] = v.z; s[r][c + 3] = v.w;
    __syncthreads();
    size_t ob = ((size_t)g * D + bj * 32 + r) * D + bi * 32 + c;
    ushort4 h, l4;
    float o0 = s[c + 0][r], o1 = s[c + 1][r], o2 = s[c + 2][r], o3 = s[c + 3][r];
    h.x = f2bf(o0); l4.x = f2bf(o0 - bf2f(h.x));
    h.y = f2bf(o1); l4.y = f2bf(o1 - bf2f(h.y));
    h.z = f2bf(o2); l4.z = f2bf(o2 - bf2f(h.z));
    h.w = f2bf(o3); l4.w = f2bf(o3 - bf2f(h.w));
    *(ushort4*)(th + ob) = h;
    *(ushort4*)(tl + ob) = l4;
    if (t < 32) {
      const float* av = asrc + (size_t)g * D + bj * 32;
      float p2 = 0.f;
#pragma unroll
      for (int cc = 0; cc < 32; ++cc) p2 += s[t][cc] * av[cc];
      atomicAdd(&wa[(size_t)g * D + bi * 32 + t], p2);
    }
  } else {
    int e = (b - 3776) * 256 + t;
    atomicAdd(&cnt[ed[e]], 1);
  }
}

// ---- fused per-node: logits + softmax + wave-parallel float4 aggregate (2x
// ---- unrolled for MLP) + ELU + split + next-layer scores. 256 thr per node.
__global__ __launch_bounds__(256) void agg_fused_k(
    const int* __restrict__ csr, const int* __restrict__ off,
    const int* __restrict__ et, const int* __restrict__ es,
    const float* __restrict__ ssrc, const float* __restrict__ sdst,
    const float* __restrict__ hr2,
    unsigned short* __restrict__ hh, unsigned short* __restrict__ hl,
    const float* __restrict__ wa_next, const float* __restrict__ adst_next,
    float* __restrict__ ssrc_o, float* __restrict__ sdst_o)
{
  __shared__ float slog[1024];
  __shared__ int soff[1024];
  __shared__ float sdn[RR];
  __shared__ float red[8];
  __shared__ float wred[4][256];
  int n = blockIdx.x, tid = threadIdx.x;
  int o0 = off[n];
  int deg = off[n + 1] - o0;
  if (deg > 1024) deg = 1024;
  if (tid < RR) sdn[tid] = sdst[(size_t)tid * NN + n];
  __syncthreads();
  for (int i = tid; i < deg; i += 256) {
    int e = csr[o0 + i];
    int t = et[e], s = es[e];
    float v = ssrc[(size_t)t * NN + s] + sdn[t];
    slog[i] = v > 0.f ? v : 0.2f * v;
    soff[i] = s * (RR * D) + t * D;
  }
  __syncthreads();
  int lane = tid & 63, wv = tid >> 6;
  float lm = -INFINITY;
  for (int i = tid; i < deg; i += 256) lm = fmaxf(lm, slog[i]);
#pragma unroll
  for (int o = 32; o; o >>= 1) lm = fmaxf(lm, __shfl_xor(lm, o));
  if (lane == 0) red[wv] = lm;
  __syncthreads();
  float m = fmaxf(fmaxf(red[0], red[1]), fmaxf(red[2], red[3]));
  float ls = 0.f;
  for (int i = tid; i < deg; i += 256) {
    float a = expf(slog[i] - m);
    slog[i] = a;
    ls += a;
  }
#pragma unroll
  for (int o = 32; o; o >>= 1) ls += __shfl_xor(ls, o);
  if (lane == 0) red[4 + wv] = ls;
  __syncthreads();
  float dinv = 1.f / (red[4] + red[5] + red[6] + red[7] + 1e-16f);
  // wave-parallel aggregation, unrolled x2: two edge streams in flight
  float4 a4 = make_float4(0.f, 0.f, 0.f, 0.f);
  float4 b4 = make_float4(0.f, 0.f, 0.f, 0.f);
  int i = wv;
  for (; i + 4 < deg; i += 8) {
    float al0 = slog[i], al1 = slog[i + 4];
    float4 r0 = ((const float4*)(hr2 + (size_t)soff[i]))[lane];
    float4 r1 = ((const float4*)(hr2 + (size_t)soff[i + 4]))[lane];
    a4.x += al0 * r0.x; a4.y += al0 * r0.y; a4.z += al0 * r0.z; a4.w += al0 * r0.w;
    b4.x += al1 * r1.x; b4.y += al1 * r1.y; b4.z += al1 * r1.z; b4.w += al1 * r1.w;
  }
  if (i < deg) {
    float al0 = slog[i];
    float4 r0 = ((const float4*)(hr2 + (size_t)soff[i]))[lane];
    a4.x += al0 * r0.x; a4.y += al0 * r0.y; a4.z += al0 * r0.z; a4.w += al0 * r0.w;
  }
  a4.x += b4.x; a4.y += b4.y; a4.z += b4.z; a4.w += b4.w;
  ((float4*)wred[wv])[lane] = a4;
  __syncthreads();
  float acc = (wred[0][tid] + wred[1][tid]) + (wred[2][tid] + wred[3][tid]);
  acc *= dinv;
  float v = acc > 0.f ? acc : expm1f(acc);
  size_t idx = (size_t)n * D + tid;
  unsigned short hb = f2bf(v);
  hh[idx] = hb;
  hl[idx] = f2bf(v - bf2f(hb));

  if (wa_next) {
    __syncthreads();
    slog[tid] = v;
    __syncthreads();
#pragma unroll
    for (int rr2 = 0; rr2 < 2; ++rr2) {
      int r = wv * 2 + rr2;
      const float* wr = wa_next + (size_t)r * D;
      const float* ar = adst_next + (size_t)r * D;
      float s1 = slog[lane] * wr[lane] + slog[lane+64] * wr[lane+64]
               + slog[lane+128] * wr[lane+128] + slog[lane+192] * wr[lane+192];
      float s2 = slog[lane] * ar[lane] + slog[lane+64] * ar[lane+64]
               + slog[lane+128] * ar[lane+128] + slog[lane+192] * ar[lane+192];
#pragma unroll
      for (int o = 32; o; o >>= 1) { s1 += __shfl_down(s1, o); s2 += __shfl_down(s2, o); }
      if (lane == 0) { ssrc_o[(size_t)r * NN + n] = s1; sdst_o[(size_t)r * NN + n] = s2; }
    }
  }
}

// ---------------- final attention scores via split-bf16 MFMA ----------------
// qk layout: [NN][512] hi/lo; q = cols [0,256), k = cols [256,512)
__global__ __launch_bounds__(256) void attn_mfma_k(
    const unsigned short* __restrict__ qkh, const unsigned short* __restrict__ qkl,
    float* __restrict__ out)
{
  int bh = blockIdx.y; int b = bh >> 3, hd = bh & 7;
  int rb = (blockIdx.x >> 3) * 64, cb = (blockIdx.x & 7) * 64;
  int t = threadIdx.x, lane = t & 63, w = t >> 6;
  int wm = w >> 1, wn = w & 1;
  int colq = hd * 32 + (lane >> 4) * 8;
  int colk = 256 + colq;
  int arow = b * SS + rb + wm * 32 + (lane & 15);
  int brow = b * SS + cb + wn * 32 + (lane & 15);

  bf16x8 aH[2], aL[2], bH[2], bL[2];
#pragma unroll
  for (int m = 0; m < 2; ++m) {
    size_t o1 = (size_t)(arow + m * 16) * 512 + colq;
    aH[m] = *(const bf16x8*)(qkh + o1);
    aL[m] = *(const bf16x8*)(qkl + o1);
    size_t o2 = (size_t)(brow + m * 16) * 512 + colk;
    bH[m] = *(const bf16x8*)(qkh + o2);
    bL[m] = *(const bf16x8*)(qkl + o2);
  }
  f32x4 acc[2][2];
#pragma unroll
  for (int m = 0; m < 2; ++m)
#pragma unroll
    for (int n = 0; n < 2; ++n) {
      acc[m][n] = (f32x4){0.f, 0.f, 0.f, 0.f};
      acc[m][n] = __builtin_amdgcn_mfma_f32_16x16x32_bf16(aH[m], bH[n], acc[m][n], 0, 0, 0);
      acc[m][n] = __builtin_amdgcn_mfma_f32_16x16x32_bf16(aL[m], bH[n], acc[m][n], 0, 0, 0);
      acc[m][n] = __builtin_amdgcn_mfma_f32_16x16x32_bf16(aH[m], bL[n], acc[m][n], 0, 0, 0);
    }
  const float scale = 0.17677669529663687f; // 1/sqrt(32)
  size_t ob = (size_t)bh * SS * SS;
#pragma unroll
  for (int m = 0; m < 2; ++m)
#pragma unroll
    for (int n = 0; n < 2; ++n) {
      int row0 = rb + wm * 32 + m * 16 + (lane >> 4) * 4;
      int col = cb + wn * 32 + n * 16 + (lane & 15);
#pragma unroll
      for (int j = 0; j < 4; ++j)
        out[ob + (size_t)(row0 + j) * SS + col] = acc[m][n][j] * scale;
    }
}

// ---------------- launcher ----------------
extern "C" void kernel_launch(void* const* d_in, const int* in_sizes, int n_in,
                              void* d_out, int out_size, void* d_ws, size_t ws_size,
                              hipStream_t stream) {
  const float* x    = (const float*)d_in[0];
  const int*   es   = (const int*)d_in[1];
  const int*   ed   = (const int*)d_in[2];
  const int*   et   = (const int*)d_in[3];
  const float* Wl   = (const float*)d_in[4];
  const float* bl   = (const float*)d_in[5];
  const float* Wgat = (const float*)d_in[6];
  const float* asr  = (const float*)d_in[7];
  const float* adt  = (const float*)d_in[8];
  const float* W1   = (const float*)d_in[9];
  const float* b1   = (const float*)d_in[10];
  const float* Wq   = (const float*)d_in[11];
  const float* bq   = (const float*)d_in[12];
  const float* Wk   = (const float*)d_in[13];
  const float* bk   = (const float*)d_in[14];
  float* out = (float*)d_out;

  char* w = (char*)d_ws;
  size_t o = 0;
  auto alloc = [&](size_t bytes) { void* p = w + o; o += (bytes + 255) & ~(size_t)255; return p; };
  unsigned short* hh    = (unsigned short*)alloc((size_t)NN * D * 2);
  unsigned short* hl    = (unsigned short*)alloc((size_t)NN * D * 2);
  unsigned short* Wgt_h = (unsigned short*)alloc((size_t)LL * RR * D * D * 2);
  unsigned short* Wgt_l = (unsigned short*)alloc((size_t)LL * RR * D * D * 2);
  unsigned short* wlh   = (unsigned short*)alloc((size_t)D * D * 2);
  unsigned short* wll   = (unsigned short*)alloc((size_t)D * D * 2);
  unsigned short* fqkh  = (unsigned short*)alloc((size_t)2 * D * D * 2);   // folded [512][256]
  unsigned short* fqkl  = (unsigned short*)alloc((size_t)2 * D * D * 2);
  float* bqk   = (float*)alloc((size_t)2 * D * 4);
  // cnt and wa adjacent (both zeroed by one memset; NN*4 is 256-aligned)
  int*   cnt   = (int*)alloc((size_t)NN * 4);
  float* wa    = (float*)alloc((size_t)LL * RR * D * 4);
  float* ssrcA = (float*)alloc((size_t)RR * NN * 4);
  float* sdstA = (float*)alloc((size_t)RR * NN * 4);
  float* ssrcB = (float*)alloc((size_t)RR * NN * 4);
  float* sdstB = (float*)alloc((size_t)RR * NN * 4);
  int*   off   = (int*)alloc((size_t)(NN + 1) * 4);
  int*   cur   = (int*)alloc((size_t)NN * 4);
  int*   csr   = (int*)alloc((size_t)EE * 4);
  // 32 MB multipurpose region
  char* big = (char*)alloc((size_t)NN * RR * D * 4);
  float*          hr2 = (float*)big;                     // [NN][R*D] during layers
  unsigned short* xh  = (unsigned short*)big;            // before layers
  unsigned short* xl  = (unsigned short*)(big + (size_t)NN * D * 2);
  unsigned short* qkh = (unsigned short*)big;            // after layers [NN][512]
  unsigned short* qkl = (unsigned short*)(big + (size_t)NN * 512 * 2);

  // one memset zeroes cnt (16 KB) + wa (32 KB) contiguously
  hipMemsetAsync(cnt, 0, (size_t)NN * 4 + (size_t)LL * RR * D * 4, stream);

  // mega prep: cvt(x,Wl) + fold + foldb + transp+wa + edge count
  prep_k<<<4032, 256, 0, stream>>>(x, xh, xl, Wl, wlh, wll, Wq, Wk, W1,
                                   fqkh, fqkl, b1, bq, bk, bqk,
                                   Wgat, asr, Wgt_h, Wgt_l, wa, ed, cnt);
  scan_k<<<1, 1024, 0, stream>>>(cnt, off, cur);
  // CSR fill + h = x @ Wl^T + bl in one launch
  fill_gemm1_k<<<512, 256, 0, stream>>>(ed, cur, csr, xh, xl, wlh, wll, bl, hh, hl);

  for (int l = 0; l < LL; ++l) {
    // RGAT GEMM 128x64 tiles (+ layer-0 scores piggybacked on first launch)
    int grid = (l == 0) ? 1024 + NN : 1024;
    rgat_scores_k<<<grid, 256, 0, stream>>>(
        hh, hl, Wgt_h + (size_t)l * RR * D * D, Wgt_l + (size_t)l * RR * D * D,
        hr2, wa, adt, ssrcA, sdstA);
    const float* wan = (l < LL - 1) ? wa + (size_t)(l + 1) * RR * D : nullptr;
    const float* adn = (l < LL - 1) ? adt + (size_t)(l + 1) * RR * D : nullptr;
    const float* sin_ = (l & 1) ? ssrcB : ssrcA;
    const float* din_ = (l & 1) ? sdstB : sdstA;
    float* sou_ = (l & 1) ? ssrcA : ssrcB;
    float* dou_ = (l & 1) ? sdstA : sdstB;
    agg_fused_k<<<NN, 256, 0, stream>>>(csr, off, et, es, sin_, din_, hr2,
                                        hh, hl, wan, adn, sou_, dou_);
  }

  // [q|k] = h @ (W{q,k}·W1)^T + (W{q,k}·b1 + b{q,k})   — one GEMM, N=512
  gemm_split<64, 64, false, true><<<dim3(8, 64), 256, 0, stream>>>(
      hh, hl, fqkh, fqkl, bqk, nullptr, qkh, qkl, NN, 512, D);

  attn_mfma_k<<<dim3(64, BB * HH), 256, 0, stream>>>(qkh, qkl, out);
}

// Round 16
// 217.322 us; speedup vs baseline: 1.1269x; 1.1269x over previous
//
#include <hip/hip_runtime.h>
#include <math.h>

#define NN 4096      // nodes = B*S
#define D 256        // DIN == DOUT
#define RR 8
#define LL 4
#define EE 65536
#define BB 8
#define SS 512
#define HH 8
#define RK 256       // RGAT GEMM K
#define RN 2048      // RGAT GEMM N (R*D)

typedef short bf16x8 __attribute__((ext_vector_type(8)));
typedef float f32x4 __attribute__((ext_vector_type(4)));

__device__ __forceinline__ unsigned short f2bf(float f) {
  unsigned u = __float_as_uint(f);
  unsigned r = (u + 0x7fffu + ((u >> 16) & 1u)) >> 16;
  return (unsigned short)r;
}
__device__ __forceinline__ float bf2f(unsigned short s) {
  return __uint_as_float(((unsigned)s) << 16);
}

__device__ __forceinline__ void gload16(unsigned short* dst, const unsigned short* src) {
  __builtin_amdgcn_global_load_lds(
      (const __attribute__((address_space(1))) void*)src,
      (__attribute__((address_space(3))) void*)dst, 16, 0, 0);
}

// ---------------- split-bf16 MFMA GEMM body (4 waves, 2x2 wave grid) --------
// C[M,N] = (Ah+Al)[M,K] * (Bh+Bl)[N,K]^T (+bias), fp32 accum, 3-term split.
// Double-buffered LDS, 1 barrier/K-step; k-slot XOR swizzle both sides.
template<int BM, int BN, bool F32OUT, bool SPLITOUT>
__device__ __forceinline__ void gemm_body(unsigned short* lds, int bx, int by,
    const unsigned short* __restrict__ Ah, const unsigned short* __restrict__ Al,
    const unsigned short* __restrict__ Bh, const unsigned short* __restrict__ Bl,
    const float* __restrict__ bias,
    float* __restrict__ C, unsigned short* __restrict__ Ch, unsigned short* __restrict__ Cl,
    int M, int N, int K)
{
  constexpr int MF = BM / 32;
  constexpr int NF = BN / 32;
  constexpr int ABUF = BM * 32;
  constexpr int BBUF = BN * 32;
  constexpr int BUFSZ = 2 * ABUF + 2 * BBUF;

  const int t = threadIdx.x;
  const int lane = t & 63;
  const int w = t >> 6;
  const int wm = w >> 1, wn = w & 1;
  const int rb = by * BM;
  const int cb = bx * BN;

  f32x4 acc[MF][NF];
#pragma unroll
  for (int m = 0; m < MF; ++m)
#pragma unroll
    for (int n = 0; n < NF; ++n)
      acc[m][n] = (f32x4){0.f, 0.f, 0.f, 0.f};

  const int srow = t >> 2;
  const int lslot = (t & 3) ^ ((srow >> 1) & 3);
  const unsigned short* gAh = Ah + (size_t)(rb + srow) * K + lslot * 8;
  const unsigned short* gAl = Al + (size_t)(rb + srow) * K + lslot * 8;
  const unsigned short* gBh = Bh + (size_t)(cb + srow) * K + lslot * 8;
  const unsigned short* gBl = Bl + (size_t)(cb + srow) * K + lslot * 8;

  auto stage = [&](int buf, int k0) {
    unsigned short* p = lds + buf * BUFSZ;
#pragma unroll
    for (int i = 0; i < BM / 64; ++i) {
      gload16(p + i * 2048 + t * 8,        gAh + (size_t)i * 64 * K + k0);
      gload16(p + ABUF + i * 2048 + t * 8, gAl + (size_t)i * 64 * K + k0);
    }
#pragma unroll
    for (int i = 0; i < BN / 64; ++i) {
      gload16(p + 2 * ABUF + i * 2048 + t * 8,        gBh + (size_t)i * 64 * K + k0);
      gload16(p + 2 * ABUF + BBUF + i * 2048 + t * 8, gBl + (size_t)i * 64 * K + k0);
    }
  };

  stage(0, 0);
  int cur = 0;
  for (int k0 = 0; k0 < K; k0 += 32) {
    __syncthreads();
    if (k0 + 32 < K) stage(cur ^ 1, k0 + 32);
    const unsigned short* p = lds + cur * BUFSZ;

    bf16x8 ah[MF], al[MF];
#pragma unroll
    for (int m = 0; m < MF; ++m) {
      int row = wm * (BM / 2) + m * 16 + (lane & 15);
      int off = row * 32 + (((lane >> 4) ^ ((row >> 1) & 3)) << 3);
      ah[m] = *(const bf16x8*)(p + off);
      al[m] = *(const bf16x8*)(p + ABUF + off);
    }
#pragma unroll
    for (int n = 0; n < NF; ++n) {
      int brow = wn * (BN / 2) + n * 16 + (lane & 15);
      int boff = brow * 32 + (((lane >> 4) ^ ((brow >> 1) & 3)) << 3);
      bf16x8 bh = *(const bf16x8*)(p + 2 * ABUF + boff);
      bf16x8 bl = *(const bf16x8*)(p + 2 * ABUF + BBUF + boff);
#pragma unroll
      for (int m = 0; m < MF; ++m) {
        acc[m][n] = __builtin_amdgcn_mfma_f32_16x16x32_bf16(ah[m], bh, acc[m][n], 0, 0, 0);
        acc[m][n] = __builtin_amdgcn_mfma_f32_16x16x32_bf16(al[m], bh, acc[m][n], 0, 0, 0);
        acc[m][n] = __builtin_amdgcn_mfma_f32_16x16x32_bf16(ah[m], bl, acc[m][n], 0, 0, 0);
      }
    }
    cur ^= 1;
  }

#pragma unroll
  for (int m = 0; m < MF; ++m) {
#pragma unroll
    for (int n = 0; n < NF; ++n) {
      int row0 = rb + wm * (BM / 2) + m * 16 + (lane >> 4) * 4;
      int col = cb + wn * (BN / 2) + n * 16 + (lane & 15);
      float bv = bias ? bias[col] : 0.f;
#pragma unroll
      for (int j = 0; j < 4; ++j) {
        float v = acc[m][n][j] + bv;
        size_t idx = (size_t)(row0 + j) * N + col;
        if (F32OUT) C[idx] = v;
        if (SPLITOUT) {
          unsigned short hb = f2bf(v);
          Ch[idx] = hb;
          Cl[idx] = f2bf(v - bf2f(hb));
        }
      }
    }
  }
}

// standalone GEMM kernel (qk projection)
template<int BM, int BN, bool F32OUT, bool SPLITOUT>
__global__ __launch_bounds__(256) void gemm_split(
    const unsigned short* __restrict__ Ah, const unsigned short* __restrict__ Al,
    const unsigned short* __restrict__ Bh, const unsigned short* __restrict__ Bl,
    const float* __restrict__ bias,
    float* __restrict__ C, unsigned short* __restrict__ Ch, unsigned short* __restrict__ Cl,
    int M, int N, int K)
{
  __shared__ unsigned short lds[2 * (2 * BM * 32 + 2 * BN * 32)];
  gemm_body<BM, BN, F32OUT, SPLITOUT>(lds, blockIdx.x, blockIdx.y,
      Ah, Al, Bh, Bl, bias, C, Ch, Cl, M, N, K);
}

// ---- merged: CSR fill (blocks 0..255) + first GEMM h=x@Wl^T+bl (blocks 256..511)
__global__ __launch_bounds__(256) void fill_gemm1_k(
    const int* __restrict__ ed, int* __restrict__ cur, int* __restrict__ csr,
    const unsigned short* __restrict__ xh, const unsigned short* __restrict__ xl,
    const unsigned short* __restrict__ wlh, const unsigned short* __restrict__ wll,
    const float* __restrict__ bl,
    unsigned short* __restrict__ hh, unsigned short* __restrict__ hl)
{
  __shared__ unsigned short lds[2 * (2 * 64 * 32 + 2 * 64 * 32)];
  int b = blockIdx.x;
  if (b < 256) {
    int e = b * 256 + threadIdx.x;
    int p = atomicAdd(&cur[ed[e]], 1);
    csr[p] = e;
  } else {
    int b2 = b - 256;
    gemm_body<64, 64, false, true>(lds, b2 & 3, b2 >> 2,
        xh, xl, wlh, wll, bl, nullptr, hh, hl, NN, D, D);
  }
}

// ------- merged: RGAT GEMM (blocks 0..511, 256 thr 4-wave 128x128 tile,
// ------- XCD-chunked swizzle) + layer-0 scores (blocks 512..4607).
__global__ __launch_bounds__(256) void rgat_scores_k(
    const unsigned short* __restrict__ Ah, const unsigned short* __restrict__ Al,
    const unsigned short* __restrict__ Bh, const unsigned short* __restrict__ Bl,
    float* __restrict__ C,
    const float* __restrict__ wa_l, const float* __restrict__ adst_l,
    float* __restrict__ ssrc, float* __restrict__ sdst)
{
  __shared__ unsigned short lds[2 * (2 * 128 * 32 + 2 * 128 * 32)];  // 64 KB
  const int b = blockIdx.x;
  const int t = threadIdx.x;
  if (b < 512) {
    // T1: chunked XCD swizzle (bijective, 512 % 8 == 0). Each XCD gets 64
    // consecutive tiles = 4 A-panels x 16 B-panels (~2.5 MB < 4 MB L2).
    int tb = (b & 7) * 64 + (b >> 3);
    gemm_body<128, 128, true, false>(lds, tb & 15, tb >> 4,
        Ah, Al, Bh, Bl, nullptr, C, nullptr, nullptr, NN, RN, RK);
  } else {
    // layer-0 scores: node n = b - 512 (A operand == split h)
    float* sh = (float*)lds;
    int n = b - 512;
    size_t idx = (size_t)n * D + t;
    sh[t] = bf2f(Ah[idx]) + bf2f(Al[idx]);
    __syncthreads();
    int lane = t & 63, wv = t >> 6;
#pragma unroll
    for (int rr = 0; rr < 2; ++rr) {
      int r = wv * 2 + rr;
      const float* wr = wa_l + (size_t)r * D;
      const float* ar = adst_l + (size_t)r * D;
      float s1 = sh[lane] * wr[lane] + sh[lane+64] * wr[lane+64]
               + sh[lane+128] * wr[lane+128] + sh[lane+192] * wr[lane+192];
      float s2 = sh[lane] * ar[lane] + sh[lane+64] * ar[lane+64]
               + sh[lane+128] * ar[lane+128] + sh[lane+192] * ar[lane+192];
#pragma unroll
      for (int o = 32; o; o >>= 1) { s1 += __shfl_down(s1, o); s2 += __shfl_down(s2, o); }
      if (lane == 0) { ssrc[(size_t)r * NN + n] = s1; sdst[(size_t)r * NN + n] = s2; }
    }
  }
}

// ---------------- CSR scan (wave-scan, 2 barriers) ----------------
__global__ __launch_bounds__(1024) void scan_k(const int* __restrict__ cnt,
    int* __restrict__ off, int* __restrict__ cur) {
  __shared__ int wsum[16];
  int t = threadIdx.x;
  int lane = t & 63, wv = t >> 6;
  int base = t * 4;
  int c0 = cnt[base], c1 = cnt[base+1], c2 = cnt[base+2], c3 = cnt[base+3];
  int s = c0 + c1 + c2 + c3;
  // inclusive wave scan of s
  int run = s;
#pragma unroll
  for (int o = 1; o < 64; o <<= 1) {
    int v = __shfl_up(run, o);
    if (lane >= o) run += v;
  }
  if (lane == 63) wsum[wv] = run;
  __syncthreads();
  if (t == 0) {
    int r = 0;
#pragma unroll
    for (int i = 0; i < 16; ++i) { int x = wsum[i]; wsum[i] = r; r += x; }
  }
  __syncthreads();
  int excl = wsum[wv] + run - s;
  off[base] = excl; off[base+1] = excl + c0; off[base+2] = excl + c0 + c1;
  off[base+3] = excl + c0 + c1 + c2;
  cur[base] = excl; cur[base+1] = excl + c0; cur[base+2] = excl + c0 + c1;
  cur[base+3] = excl + c0 + c1 + c2;
  if (t == 1023) off[NN] = EE;
}

// ------- mega prep: cvt(x,Wl) + fold + foldb + transp+wa + edge count --------
// blocks [0,1024): x split; [1024,1088): Wl split; [1088,1600): fold Wq/Wk*W1;
// [1600,1728): fold bias; [1728,3776): Wgat transpose-split + wa dots;
// [3776,4032): edge count. (cnt and wa zeroed by the preceding memset.)
__global__ __launch_bounds__(256) void prep_k(
    const float* __restrict__ x, unsigned short* __restrict__ xh, unsigned short* __restrict__ xl,
    const float* __restrict__ Wl, unsigned short* __restrict__ wlh, unsigned short* __restrict__ wll,
    const float* __restrict__ Wq, const float* __restrict__ Wk, const float* __restrict__ W1,
    unsigned short* __restrict__ fqkh, unsigned short* __restrict__ fqkl,
    const float* __restrict__ b1, const float* __restrict__ bq, const float* __restrict__ bk,
    float* __restrict__ bqk,
    const float* __restrict__ Wgat, const float* __restrict__ asrc,
    unsigned short* __restrict__ th, unsigned short* __restrict__ tl,
    float* __restrict__ wa,
    const int* __restrict__ ed, int* __restrict__ cnt)
{
  __shared__ float s[32][33];
  int b = blockIdx.x, t = threadIdx.x;
  if (b < 1088) {
    const float* src; unsigned short* hi; unsigned short* lo; int i;
    if (b < 1024) { src = x;  hi = xh;  lo = xl;  i = b * 256 + t; }
    else          { src = Wl; hi = wlh; lo = wll; i = (b - 1024) * 256 + t; }
    float4 v = ((const float4*)src)[i];
    ushort4 h, l;
    h.x = f2bf(v.x); l.x = f2bf(v.x - bf2f(h.x));
    h.y = f2bf(v.y); l.y = f2bf(v.y - bf2f(h.y));
    h.z = f2bf(v.z); l.z = f2bf(v.z - bf2f(h.z));
    h.w = f2bf(v.w); l.w = f2bf(v.w - bf2f(h.w));
    ((ushort4*)hi)[i] = h;
    ((ushort4*)lo)[i] = l;
  } else if (b < 1600) {
    int b2 = b - 1088;
    int j = (b2 & 3) * 64 + (t & 63);
    int i = (b2 >> 2) * 4 + (t >> 6);
    const float* row = i < 256 ? Wq + (size_t)i * D : Wk + (size_t)(i - 256) * D;
    float sm = 0.f;
    for (int k = 0; k < D; ++k) sm += row[k] * W1[(size_t)k * D + j];
    size_t idx = (size_t)i * D + j;
    unsigned short hb = f2bf(sm);
    fqkh[idx] = hb;
    fqkl[idx] = f2bf(sm - bf2f(hb));
  } else if (b < 1728) {
    int b2 = b - 1600;
    int idx = b2 * 4 + (t >> 6);
    int lane = t & 63;
    const float* row = idx < 256 ? Wq + (size_t)idx * D : Wk + (size_t)(idx - 256) * D;
    float sm = 0.f;
    for (int i = lane; i < D; i += 64) sm += row[i] * b1[i];
#pragma unroll
    for (int o = 32; o; o >>= 1) sm += __shfl_down(sm, o);
    if (lane == 0) bqk[idx] = sm + (idx < 256 ? bq[idx] : bk[idx - 256]);
  } else if (b < 3776) {
    int b2 = b - 1728;                 // 0..2047: g = l*8+r in [0,32)
    int g = b2 >> 6, bi = (b2 >> 3) & 7, bj = b2 & 7;
    int r = t >> 3, c = (t & 7) * 4;
    float4 v = *(const float4*)(Wgat + ((size_t)g * D + bi * 32 + r) * D + bj * 32 + c);
    s[r][c + 0] = v.x; s[r][c + 1] = v.y; s[r][c + 2] = v.z; s[r][c + 3] = v.w;
    __syncthreads();
    size_t ob = ((size_t)g * D + bj * 32 + r) * D + bi * 32 + c;
    ushort4 h, l4;
    float o0 = s[c + 0][r], o1 = s[c + 1][r], o2 = s[c + 2][r], o3 = s[c + 3][r];
    h.x = f2bf(o0); l4.x = f2bf(o0 - bf2f(h.x));
    h.y = f2bf(o1); l4.y = f2bf(o1 - bf2f(h.y));
    h.z = f2bf(o2); l4.z = f2bf(o2 - bf2f(h.z));
    h.w = f2bf(o3); l4.w = f2bf(o3 - bf2f(h.w));
    *(ushort4*)(th + ob) = h;
    *(ushort4*)(tl + ob) = l4;
    if (t < 32) {
      const float* av = asrc + (size_t)g * D + bj * 32;
      float p2 = 0.f;
#pragma unroll
      for (int cc = 0; cc < 32; ++cc) p2 += s[t][cc] * av[cc];
      atomicAdd(&wa[(size_t)g * D + bi * 32 + t], p2);
    }
  } else {
    int e = (b - 3776) * 256 + t;
    atomicAdd(&cnt[ed[e]], 1);
  }
}

// ---- fused per-node: logits + softmax + wave-parallel float4 aggregate (2x
// ---- unrolled for MLP) + ELU + split + next-layer scores. 256 thr per node.
__global__ __launch_bounds__(256) void agg_fused_k(
    const int* __restrict__ csr, const int* __restrict__ off,
    const int* __restrict__ et, const int* __restrict__ es,
    const float* __restrict__ ssrc, const float* __restrict__ sdst,
    const float* __restrict__ hr2,
    unsigned short* __restrict__ hh, unsigned short* __restrict__ hl,
    const float* __restrict__ wa_next, const float* __restrict__ adst_next,
    float* __restrict__ ssrc_o, float* __restrict__ sdst_o)
{
  __shared__ float slog[1024];
  __shared__ int soff[1024];
  __shared__ float sdn[RR];
  __shared__ float red[8];
  __shared__ float wred[4][256];
  int n = blockIdx.x, tid = threadIdx.x;
  int o0 = off[n];
  int deg = off[n + 1] - o0;
  if (deg > 1024) deg = 1024;
  if (tid < RR) sdn[tid] = sdst[(size_t)tid * NN + n];
  __syncthreads();
  for (int i = tid; i < deg; i += 256) {
    int e = csr[o0 + i];
    int t = et[e], s = es[e];
    float v = ssrc[(size_t)t * NN + s] + sdn[t];
    slog[i] = v > 0.f ? v : 0.2f * v;
    soff[i] = s * (RR * D) + t * D;
  }
  __syncthreads();
  int lane = tid & 63, wv = tid >> 6;
  float lm = -INFINITY;
  for (int i = tid; i < deg; i += 256) lm = fmaxf(lm, slog[i]);
#pragma unroll
  for (int o = 32; o; o >>= 1) lm = fmaxf(lm, __shfl_xor(lm, o));
  if (lane == 0) red[wv] = lm;
  __syncthreads();
  float m = fmaxf(fmaxf(red[0], red[1]), fmaxf(red[2], red[3]));
  float ls = 0.f;
  for (int i = tid; i < deg; i += 256) {
    float a = expf(slog[i] - m);
    slog[i] = a;
    ls += a;
  }
#pragma unroll
  for (int o = 32; o; o >>= 1) ls += __shfl_xor(ls, o);
  if (lane == 0) red[4 + wv] = ls;
  __syncthreads();
  float dinv = 1.f / (red[4] + red[5] + red[6] + red[7] + 1e-16f);
  // wave-parallel aggregation, unrolled x2: two edge streams in flight
  float4 a4 = make_float4(0.f, 0.f, 0.f, 0.f);
  float4 b4 = make_float4(0.f, 0.f, 0.f, 0.f);
  int i = wv;
  for (; i + 4 < deg; i += 8) {
    float al0 = slog[i], al1 = slog[i + 4];
    float4 r0 = ((const float4*)(hr2 + (size_t)soff[i]))[lane];
    float4 r1 = ((const float4*)(hr2 + (size_t)soff[i + 4]))[lane];
    a4.x += al0 * r0.x; a4.y += al0 * r0.y; a4.z += al0 * r0.z; a4.w += al0 * r0.w;
    b4.x += al1 * r1.x; b4.y += al1 * r1.y; b4.z += al1 * r1.z; b4.w += al1 * r1.w;
  }
  if (i < deg) {
    float al0 = slog[i];
    float4 r0 = ((const float4*)(hr2 + (size_t)soff[i]))[lane];
    a4.x += al0 * r0.x; a4.y += al0 * r0.y; a4.z += al0 * r0.z; a4.w += al0 * r0.w;
  }
  a4.x += b4.x; a4.y += b4.y; a4.z += b4.z; a4.w += b4.w;
  ((float4*)wred[wv])[lane] = a4;
  __syncthreads();
  float acc = (wred[0][tid] + wred[1][tid]) + (wred[2][tid] + wred[3][tid]);
  acc *= dinv;
  float v = acc > 0.f ? acc : expm1f(acc);
  size_t idx = (size_t)n * D + tid;
  unsigned short hb = f2bf(v);
  hh[idx] = hb;
  hl[idx] = f2bf(v - bf2f(hb));

  if (wa_next) {
    __syncthreads();
    slog[tid] = v;
    __syncthreads();
#pragma unroll
    for (int rr2 = 0; rr2 < 2; ++rr2) {
      int r = wv * 2 + rr2;
      const float* wr = wa_next + (size_t)r * D;
      const float* ar = adst_next + (size_t)r * D;
      float s1 = slog[lane] * wr[lane] + slog[lane+64] * wr[lane+64]
               + slog[lane+128] * wr[lane+128] + slog[lane+192] * wr[lane+192];
      float s2 = slog[lane] * ar[lane] + slog[lane+64] * ar[lane+64]
               + slog[lane+128] * ar[lane+128] + slog[lane+192] * ar[lane+192];
#pragma unroll
      for (int o = 32; o; o >>= 1) { s1 += __shfl_down(s1, o); s2 += __shfl_down(s2, o); }
      if (lane == 0) { ssrc_o[(size_t)r * NN + n] = s1; sdst_o[(size_t)r * NN + n] = s2; }
    }
  }
}

// ---------------- final attention scores via split-bf16 MFMA ----------------
// qk layout: [NN][512] hi/lo; q = cols [0,256), k = cols [256,512)
__global__ __launch_bounds__(256) void attn_mfma_k(
    const unsigned short* __restrict__ qkh, const unsigned short* __restrict__ qkl,
    float* __restrict__ out)
{
  int bh = blockIdx.y; int b = bh >> 3, hd = bh & 7;
  int rb = (blockIdx.x >> 3) * 64, cb = (blockIdx.x & 7) * 64;
  int t = threadIdx.x, lane = t & 63, w = t >> 6;
  int wm = w >> 1, wn = w & 1;
  int colq = hd * 32 + (lane >> 4) * 8;
  int colk = 256 + colq;
  int arow = b * SS + rb + wm * 32 + (lane & 15);
  int brow = b * SS + cb + wn * 32 + (lane & 15);

  bf16x8 aH[2], aL[2], bH[2], bL[2];
#pragma unroll
  for (int m = 0; m < 2; ++m) {
    size_t o1 = (size_t)(arow + m * 16) * 512 + colq;
    aH[m] = *(const bf16x8*)(qkh + o1);
    aL[m] = *(const bf16x8*)(qkl + o1);
    size_t o2 = (size_t)(brow + m * 16) * 512 + colk;
    bH[m] = *(const bf16x8*)(qkh + o2);
    bL[m] = *(const bf16x8*)(qkl + o2);
  }
  f32x4 acc[2][2];
#pragma unroll
  for (int m = 0; m < 2; ++m)
#pragma unroll
    for (int n = 0; n < 2; ++n) {
      acc[m][n] = (f32x4){0.f, 0.f, 0.f, 0.f};
      acc[m][n] = __builtin_amdgcn_mfma_f32_16x16x32_bf16(aH[m], bH[n], acc[m][n], 0, 0, 0);
      acc[m][n] = __builtin_amdgcn_mfma_f32_16x16x32_bf16(aL[m], bH[n], acc[m][n], 0, 0, 0);
      acc[m][n] = __builtin_amdgcn_mfma_f32_16x16x32_bf16(aH[m], bL[n], acc[m][n], 0, 0, 0);
    }
  const float scale = 0.17677669529663687f; // 1/sqrt(32)
  size_t ob = (size_t)bh * SS * SS;
#pragma unroll
  for (int m = 0; m < 2; ++m)
#pragma unroll
    for (int n = 0; n < 2; ++n) {
      int row0 = rb + wm * 32 + m * 16 + (lane >> 4) * 4;
      int col = cb + wn * 32 + n * 16 + (lane & 15);
#pragma unroll
      for (int j = 0; j < 4; ++j)
        out[ob + (size_t)(row0 + j) * SS + col] = acc[m][n][j] * scale;
    }
}

// ---------------- launcher ----------------
extern "C" void kernel_launch(void* const* d_in, const int* in_sizes, int n_in,
                              void* d_out, int out_size, void* d_ws, size_t ws_size,
                              hipStream_t stream) {
  const float* x    = (const float*)d_in[0];
  const int*   es   = (const int*)d_in[1];
  const int*   ed   = (const int*)d_in[2];
  const int*   et   = (const int*)d_in[3];
  const float* Wl   = (const float*)d_in[4];
  const float* bl   = (const float*)d_in[5];
  const float* Wgat = (const float*)d_in[6];
  const float* asr  = (const float*)d_in[7];
  const float* adt  = (const float*)d_in[8];
  const float* W1   = (const float*)d_in[9];
  const float* b1   = (const float*)d_in[10];
  const float* Wq   = (const float*)d_in[11];
  const float* bq   = (const float*)d_in[12];
  const float* Wk   = (const float*)d_in[13];
  const float* bk   = (const float*)d_in[14];
  float* out = (float*)d_out;

  char* w = (char*)d_ws;
  size_t o = 0;
  auto alloc = [&](size_t bytes) { void* p = w + o; o += (bytes + 255) & ~(size_t)255; return p; };
  unsigned short* hh    = (unsigned short*)alloc((size_t)NN * D * 2);
  unsigned short* hl    = (unsigned short*)alloc((size_t)NN * D * 2);
  unsigned short* Wgt_h = (unsigned short*)alloc((size_t)LL * RR * D * D * 2);
  unsigned short* Wgt_l = (unsigned short*)alloc((size_t)LL * RR * D * D * 2);
  unsigned short* wlh   = (unsigned short*)alloc((size_t)D * D * 2);
  unsigned short* wll   = (unsigned short*)alloc((size_t)D * D * 2);
  unsigned short* fqkh  = (unsigned short*)alloc((size_t)2 * D * D * 2);   // folded [512][256]
  unsigned short* fqkl  = (unsigned short*)alloc((size_t)2 * D * D * 2);
  float* bqk   = (float*)alloc((size_t)2 * D * 4);
  // cnt and wa adjacent (both zeroed by one memset; NN*4 is 256-aligned)
  int*   cnt   = (int*)alloc((size_t)NN * 4);
  float* wa    = (float*)alloc((size_t)LL * RR * D * 4);
  float* ssrcA = (float*)alloc((size_t)RR * NN * 4);
  float* sdstA = (float*)alloc((size_t)RR * NN * 4);
  float* ssrcB = (float*)alloc((size_t)RR * NN * 4);
  float* sdstB = (float*)alloc((size_t)RR * NN * 4);
  int*   off   = (int*)alloc((size_t)(NN + 1) * 4);
  int*   cur   = (int*)alloc((size_t)NN * 4);
  int*   csr   = (int*)alloc((size_t)EE * 4);
  // 32 MB multipurpose region
  char* big = (char*)alloc((size_t)NN * RR * D * 4);
  float*          hr2 = (float*)big;                     // [NN][R*D] during layers
  unsigned short* xh  = (unsigned short*)big;            // before layers
  unsigned short* xl  = (unsigned short*)(big + (size_t)NN * D * 2);
  unsigned short* qkh = (unsigned short*)big;            // after layers [NN][512]
  unsigned short* qkl = (unsigned short*)(big + (size_t)NN * 512 * 2);

  // one memset zeroes cnt (16 KB) + wa (32 KB) contiguously
  hipMemsetAsync(cnt, 0, (size_t)NN * 4 + (size_t)LL * RR * D * 4, stream);

  // mega prep: cvt(x,Wl) + fold + foldb + transp+wa + edge count
  prep_k<<<4032, 256, 0, stream>>>(x, xh, xl, Wl, wlh, wll, Wq, Wk, W1,
                                   fqkh, fqkl, b1, bq, bk, bqk,
                                   Wgat, asr, Wgt_h, Wgt_l, wa, ed, cnt);
  scan_k<<<1, 1024, 0, stream>>>(cnt, off, cur);
  // CSR fill + h = x @ Wl^T + bl in one launch
  fill_gemm1_k<<<512, 256, 0, stream>>>(ed, cur, csr, xh, xl, wlh, wll, bl, hh, hl);

  for (int l = 0; l < LL; ++l) {
    // RGAT GEMM (+ layer-0 scores piggybacked on the first launch)
    int grid = (l == 0) ? 512 + NN : 512;
    rgat_scores_k<<<grid, 256, 0, stream>>>(
        hh, hl, Wgt_h + (size_t)l * RR * D * D, Wgt_l + (size_t)l * RR * D * D,
        hr2, wa, adt, ssrcA, sdstA);
    const float* wan = (l < LL - 1) ? wa + (size_t)(l + 1) * RR * D : nullptr;
    const float* adn = (l < LL - 1) ? adt + (size_t)(l + 1) * RR * D : nullptr;
    const float* sin_ = (l & 1) ? ssrcB : ssrcA;
    const float* din_ = (l & 1) ? sdstB : sdstA;
    float* sou_ = (l & 1) ? ssrcA : ssrcB;
    float* dou_ = (l & 1) ? sdstA : sdstB;
    agg_fused_k<<<NN, 256, 0, stream>>>(csr, off, et, es, sin_, din_, hr2,
                                        hh, hl, wan, adn, sou_, dou_);
  }

  // [q|k] = h @ (W{q,k}·W1)^T + (W{q,k}·b1 + b{q,k})   — one GEMM, N=512
  gemm_split<64, 64, false, true><<<dim3(8, 64), 256, 0, stream>>>(
      hh, hl, fqkh, fqkl, bqk, nullptr, qkh, qkl, NN, 512, D);

  attn_mfma_k<<<dim3(64, BB * HH), 256, 0, stream>>>(qkh, qkl, out);
}